// Round 1
// baseline (2270.644 us; speedup 1.0000x reference)
//
#include <hip/hip_runtime.h>

constexpr int NN = 100000;   // nodes
constexpr int NE = 3200000;  // edges
constexpr int NG = 256;      // graphs

// ---------- degree / norm ----------
__global__ void k_fill1(float* __restrict__ p, int n) {
  int i = blockIdx.x * blockDim.x + threadIdx.x;
  if (i < n) p[i] = 1.0f;
}

__global__ void k_deg(const int* __restrict__ dst, float* __restrict__ deg, int E) {
  int i = blockIdx.x * blockDim.x + threadIdx.x;
  int stride = gridDim.x * blockDim.x;
  for (; i < E; i += stride) atomicAdd(&deg[dst[i]], 1.0f);
}

__global__ void k_rsqrt(float* __restrict__ p, int n) {
  int i = blockIdx.x * blockDim.x + threadIdx.x;
  if (i < n) p[i] = rsqrtf(p[i]);  // deg >= 1 always (self-loop)
}

// ---------- dense transform t = h @ W ----------
template <int IN, int OUT, int ROWS>
__global__ void k_mm(const float* __restrict__ h, const float* __restrict__ W,
                     float* __restrict__ t, int n) {
  __shared__ float Ws[IN * OUT];
  __shared__ float Hs[ROWS][IN];
  const int tid = threadIdx.x;
  const int NT = ROWS * OUT;
  for (int i = tid; i < IN * OUT; i += NT) Ws[i] = W[i];
  const int row0 = blockIdx.x * ROWS;
  for (int i = tid; i < ROWS * IN; i += NT) {
    int rr = i / IN, kk = i - rr * IN;
    int gr = row0 + rr;
    Hs[rr][kk] = (gr < n) ? h[gr * IN + kk] : 0.0f;
  }
  __syncthreads();
  const int r = tid / OUT, c = tid - r * OUT;
  const int row = row0 + r;
  if (row < n) {
    float acc = 0.0f;
#pragma unroll
    for (int k = 0; k < IN; ++k) acc += Hs[r][k] * Ws[k * OUT + c];
    t[row * OUT + c] = acc;
  }
}

// ---------- self-loop init: out[v] = t[v] * dinv[v]^2 ----------
template <int LOGW>
__global__ void k_selfinit(const float* __restrict__ t, const float* __restrict__ dinv,
                           float* __restrict__ out, int n) {
  int i = blockIdx.x * blockDim.x + threadIdx.x;
  if (i < (n << LOGW)) {
    int v = i >> LOGW;
    float di = dinv[v];
    out[i] = t[i] * di * di;
  }
}

// ---------- edge scatter: out[dst] += t[src] * dinv[src]*dinv[dst] ----------
template <int LOGW>
__global__ void k_scatter(const int* __restrict__ src, const int* __restrict__ dst,
                          const float* __restrict__ dinv, const float* __restrict__ t,
                          float* __restrict__ out, int E) {
  const int W = 1 << LOGW;
  int i = blockIdx.x * blockDim.x + threadIdx.x;
  const int stride = gridDim.x * blockDim.x;
  const int total = E << LOGW;
  for (; i < total; i += stride) {
    int e = i >> LOGW;
    int f = i & (W - 1);
    int s = src[e], d = dst[e];
    float nrm = dinv[s] * dinv[d];
    atomicAdd(&out[d * W + f], t[s * W + f] * nrm);
  }
}

// ---------- bias (+relu) ----------
template <int W, bool RELU>
__global__ void k_bias(float* __restrict__ h, const float* __restrict__ b, int n) {
  int i = blockIdx.x * blockDim.x + threadIdx.x;
  if (i < n * W) {
    int f = i % W;
    float v = h[i] + b[f];
    h[i] = RELU ? fmaxf(v, 0.0f) : v;
  }
}

// ---------- pooling ----------
__global__ void k_zero(float* __restrict__ p, int n) {
  int i = blockIdx.x * blockDim.x + threadIdx.x;
  if (i < n) p[i] = 0.0f;
}

__global__ void k_pool(const float* __restrict__ h, const int* __restrict__ batch,
                       float* __restrict__ psum, float* __restrict__ pcnt, int n) {
  int i = blockIdx.x * blockDim.x + threadIdx.x;
  if (i < n * 32) {
    int node = i >> 5;
    int f = i & 31;
    int g = batch[node];
    atomicAdd(&psum[g * 32 + f], h[i]);
    if (f == 0) atomicAdd(&pcnt[g], 1.0f);
  }
}

__global__ void k_finalize(const float* __restrict__ psum, const float* __restrict__ pcnt,
                           float* __restrict__ out) {
  int i = blockIdx.x * blockDim.x + threadIdx.x;
  if (i < NG * 32) {
    int g = i >> 5;
    out[i] = psum[i] / fmaxf(pcnt[g], 1.0f);
  }
}

extern "C" void kernel_launch(void* const* d_in, const int* in_sizes, int n_in,
                              void* d_out, int out_size, void* d_ws, size_t ws_size,
                              hipStream_t stream) {
  const float* x  = (const float*)d_in[0];
  const int*   ei = (const int*)d_in[1];
  const int* batch = (const int*)d_in[2];
  const float* W1 = (const float*)d_in[3];
  const float* b1 = (const float*)d_in[4];
  const float* W2 = (const float*)d_in[5];
  const float* b2 = (const float*)d_in[6];
  const float* W3 = (const float*)d_in[7];
  const float* b3 = (const float*)d_in[8];
  float* out = (float*)d_out;

  const int* src = ei;        // edge_index[0]
  const int* dst = ei + NE;   // edge_index[1]

  float* ws   = (float*)d_ws;
  float* dinv = ws;                  // NN floats
  float* bufT = ws + 100352;         // NN*64 (aligned start)
  float* bufH = bufT + NN * 64;      // NN*64
  float* psum = bufH + NN * 64;      // NG*32
  float* pcnt = psum + NG * 32;      // NG

  const int B = 256;
  auto cdiv = [](int a, int b) { return (a + b - 1) / b; };

  // degree + rsqrt
  k_fill1<<<cdiv(NN, B), B, 0, stream>>>(dinv, NN);
  k_deg<<<2048, B, 0, stream>>>(dst, dinv, NE);
  k_rsqrt<<<cdiv(NN, B), B, 0, stream>>>(dinv, NN);

  // ---- layer 1: x(13) -> 64, relu ----
  k_mm<13, 64, 4><<<cdiv(NN, 4), B, 0, stream>>>(x, W1, bufT, NN);
  k_selfinit<6><<<cdiv(NN * 64, B), B, 0, stream>>>(bufT, dinv, bufH, NN);
  k_scatter<6><<<8192, B, 0, stream>>>(src, dst, dinv, bufT, bufH, NE);
  k_bias<64, true><<<cdiv(NN * 64, B), B, 0, stream>>>(bufH, b1, NN);

  // ---- layer 2: 64 -> 64, relu ----
  k_mm<64, 64, 4><<<cdiv(NN, 4), B, 0, stream>>>(bufH, W2, bufT, NN);
  k_selfinit<6><<<cdiv(NN * 64, B), B, 0, stream>>>(bufT, dinv, bufH, NN);
  k_scatter<6><<<8192, B, 0, stream>>>(src, dst, dinv, bufT, bufH, NE);
  k_bias<64, true><<<cdiv(NN * 64, B), B, 0, stream>>>(bufH, b2, NN);

  // ---- layer 3: 64 -> 32, no relu ----
  k_mm<64, 32, 8><<<cdiv(NN, 8), B, 0, stream>>>(bufH, W3, bufT, NN);
  k_selfinit<5><<<cdiv(NN * 32, B), B, 0, stream>>>(bufT, dinv, bufH, NN);
  k_scatter<5><<<8192, B, 0, stream>>>(src, dst, dinv, bufT, bufH, NE);
  k_bias<32, false><<<cdiv(NN * 32, B), B, 0, stream>>>(bufH, b3, NN);

  // ---- global mean pool ----
  k_zero<<<cdiv(NG * 32 + NG, B), B, 0, stream>>>(psum, NG * 32 + NG);
  k_pool<<<cdiv(NN * 32, B), B, 0, stream>>>(bufH, batch, psum, pcnt, NN);
  k_finalize<<<cdiv(NG * 32, B), B, 0, stream>>>(psum, pcnt, out);
}

// Round 2
// 988.334 us; speedup vs baseline: 2.2974x; 2.2974x over previous
//
#include <hip/hip_runtime.h>

constexpr int NN = 100000;   // nodes
constexpr int NE = 3200000;  // edges
constexpr int NG = 256;      // graphs

// ---------- zero / histogram / norm ----------
__global__ void k_zero_i(int* __restrict__ p, int n) {
  int i = blockIdx.x * blockDim.x + threadIdx.x;
  if (i < n) p[i] = 0;
}
__global__ void k_zero_f(float* __restrict__ p, int n) {
  int i = blockIdx.x * blockDim.x + threadIdx.x;
  if (i < n) p[i] = 0.0f;
}

__global__ void k_degi(const int* __restrict__ dst, int* __restrict__ degi, int E) {
  int i = blockIdx.x * blockDim.x + threadIdx.x;
  int stride = gridDim.x * blockDim.x;
  for (; i < E; i += stride) atomicAdd(&degi[dst[i]], 1);
}

__global__ void k_dinv(const int* __restrict__ degi, float* __restrict__ dinv, int n) {
  int i = blockIdx.x * blockDim.x + threadIdx.x;
  if (i < n) dinv[i] = rsqrtf((float)(degi[i] + 1));  // +1 self-loop
}

// ---------- single-block exclusive scan of degi -> rowstart[NN+1] ----------
__global__ void k_scan(const int* __restrict__ degi, int* __restrict__ rowstart) {
  constexpr int T = 1024;
  __shared__ int part[T];
  const int tid = threadIdx.x;
  const int chunk = (NN + T - 1) / T;
  const int lo = tid * chunk, hi = min(lo + chunk, NN);
  int s = 0;
  for (int i = lo; i < hi; ++i) s += degi[i];
  part[tid] = s;
  __syncthreads();
  for (int off = 1; off < T; off <<= 1) {
    int v = part[tid];
    int u = (tid >= off) ? part[tid - off] : 0;
    __syncthreads();
    part[tid] = v + u;
    __syncthreads();
  }
  int base = (tid > 0) ? part[tid - 1] : 0;
  for (int i = lo; i < hi; ++i) {
    rowstart[i] = base;
    base += degi[i];
  }
  if (tid == T - 1) rowstart[NN] = base;
}

// ---------- CSR fill: bucket edges by dst ----------
__global__ void k_fillcsr(const int* __restrict__ src, const int* __restrict__ dst,
                          const int* __restrict__ rowstart, int* __restrict__ cursor,
                          const float* __restrict__ dinv,
                          int* __restrict__ csr_src, float* __restrict__ csr_nrm, int E) {
  int i = blockIdx.x * blockDim.x + threadIdx.x;
  int stride = gridDim.x * blockDim.x;
  for (; i < E; i += stride) {
    int s = src[i], d = dst[i];
    int p = rowstart[d] + atomicAdd(&cursor[d], 1);
    csr_src[p] = s;
    csr_nrm[p] = dinv[s] * dinv[d];
  }
}

// ---------- dense transform t = h @ W ----------
template <int IN, int OUT, int ROWS>
__global__ void k_mm(const float* __restrict__ h, const float* __restrict__ W,
                     float* __restrict__ t, int n) {
  __shared__ float Ws[IN * OUT];
  __shared__ float Hs[ROWS][IN];
  const int tid = threadIdx.x;
  const int NT = ROWS * OUT;
  for (int i = tid; i < IN * OUT; i += NT) Ws[i] = W[i];
  const int row0 = blockIdx.x * ROWS;
  for (int i = tid; i < ROWS * IN; i += NT) {
    int rr = i / IN, kk = i - rr * IN;
    int gr = row0 + rr;
    Hs[rr][kk] = (gr < n) ? h[gr * IN + kk] : 0.0f;
  }
  __syncthreads();
  const int r = tid / OUT, c = tid - r * OUT;
  const int row = row0 + r;
  if (row < n) {
    float acc = 0.0f;
#pragma unroll
    for (int k = 0; k < IN; ++k) acc += Hs[r][k] * Ws[k * OUT + c];
    t[row * OUT + c] = acc;
  }
}

// ---------- gather aggregation, 64 feats: one wave per node ----------
// out[v] = relu( sum_{e in CSR[v]} t[src]*nrm + t[v]*dinv[v]^2 + b )
template <bool RELU>
__global__ void k_gather64(const float* __restrict__ t, const int* __restrict__ rowstart,
                           const int* __restrict__ csr_src, const float* __restrict__ csr_nrm,
                           const float* __restrict__ dinv, const float* __restrict__ b,
                           float* __restrict__ out) {
  const int wave = (blockIdx.x * blockDim.x + threadIdx.x) >> 6;
  const int lane = threadIdx.x & 63;
  if (wave >= NN) return;
  const int r0 = rowstart[wave], r1 = rowstart[wave + 1];
  const float di = dinv[wave];
  float acc = t[wave * 64 + lane] * di * di;
  int e = r0;
  for (; e + 3 < r1; e += 4) {
    int s0 = csr_src[e], s1 = csr_src[e + 1], s2 = csr_src[e + 2], s3 = csr_src[e + 3];
    float w0 = csr_nrm[e], w1 = csr_nrm[e + 1], w2 = csr_nrm[e + 2], w3 = csr_nrm[e + 3];
    float v0 = t[s0 * 64 + lane], v1 = t[s1 * 64 + lane];
    float v2 = t[s2 * 64 + lane], v3 = t[s3 * 64 + lane];
    acc += v0 * w0 + v1 * w1 + v2 * w2 + v3 * w3;
  }
  for (; e < r1; ++e) acc += t[csr_src[e] * 64 + lane] * csr_nrm[e];
  float v = acc + b[lane];
  out[wave * 64 + lane] = RELU ? fmaxf(v, 0.0f) : v;
}

// ---------- layer-3 gather (32 feats) fused with mean-pool partial sums ----------
__global__ void k_gather32_pool(const float* __restrict__ t, const int* __restrict__ rowstart,
                                const int* __restrict__ csr_src, const float* __restrict__ csr_nrm,
                                const float* __restrict__ dinv, const float* __restrict__ b,
                                const int* __restrict__ batch, float* __restrict__ psum) {
  const int wave = (blockIdx.x * blockDim.x + threadIdx.x) >> 6;
  const int lane = threadIdx.x & 63;
  if (wave >= NN) return;
  const int f = lane & 31, j = lane >> 5;  // two half-waves split edges
  const int r0 = rowstart[wave], r1 = rowstart[wave + 1];
  const float di = dinv[wave];
  float acc = (j == 0) ? t[wave * 32 + f] * di * di : 0.0f;
  int e = r0 + j;
  for (; e + 3 < r1; e += 4) {  // each half-wave strides by 2, unroll 2
    int s0 = csr_src[e], s1 = csr_src[e + 2];
    float w0 = csr_nrm[e], w1 = csr_nrm[e + 2];
    acc += t[s0 * 32 + f] * w0 + t[s1 * 32 + f] * w1;
  }
  for (; e < r1; e += 2) acc += t[csr_src[e] * 32 + f] * csr_nrm[e];
  acc += __shfl_xor(acc, 32, 64);  // combine half-waves
  if (j == 0) {
    atomicAdd(&psum[batch[wave] * 32 + f], acc + b[f]);
  }
}

// ---------- counts from sorted batch + final divide ----------
__global__ void k_finalize(const float* __restrict__ psum, const int* __restrict__ batch,
                           float* __restrict__ out) {
  int i = blockIdx.x * blockDim.x + threadIdx.x;
  if (i >= NG * 32) return;
  int g = i >> 5;
  // lower_bound(g) / lower_bound(g+1) on sorted batch
  int lo = 0, hi = NN;
  while (lo < hi) { int m = (lo + hi) >> 1; if (batch[m] < g) lo = m + 1; else hi = m; }
  int a = lo;
  lo = 0; hi = NN;
  while (lo < hi) { int m = (lo + hi) >> 1; if (batch[m] < g + 1) lo = m + 1; else hi = m; }
  int cnt = lo - a;
  out[i] = psum[i] / fmaxf((float)cnt, 1.0f);
}

extern "C" void kernel_launch(void* const* d_in, const int* in_sizes, int n_in,
                              void* d_out, int out_size, void* d_ws, size_t ws_size,
                              hipStream_t stream) {
  const float* x  = (const float*)d_in[0];
  const int*   ei = (const int*)d_in[1];
  const int* batch = (const int*)d_in[2];
  const float* W1 = (const float*)d_in[3];
  const float* b1 = (const float*)d_in[4];
  const float* W2 = (const float*)d_in[5];
  const float* b2 = (const float*)d_in[6];
  const float* W3 = (const float*)d_in[7];
  const float* b3 = (const float*)d_in[8];
  float* out = (float*)d_out;

  const int* src = ei;        // edge_index[0]
  const int* dst = ei + NE;   // edge_index[1]

  // workspace layout (element offsets, 4B each)
  float* ws = (float*)d_ws;
  float* dinv     = ws;                          // NN
  int*   degi     = (int*)(ws + 100352);         // NN
  int*   rowstart = (int*)(ws + 200704);         // NN+1
  int*   cursor   = (int*)(ws + 301056);         // NN
  int*   csr_src  = (int*)(ws + 401408);         // NE
  float* csr_nrm  = ws + 3601408;                // NE
  float* bufT     = ws + 6801408;                // NN*64
  float* bufH     = ws + 13201408;               // NN*64
  float* psum     = ws + 19601408;               // NG*32

  const int B = 256;
  auto cdiv = [](int a, int b) { return (a + b - 1) / b; };

  // ---- build norm + CSR (shared across all 3 layers) ----
  k_zero_i<<<cdiv(2 * NN, B), B, 0, stream>>>(degi, NN);
  k_zero_i<<<cdiv(NN, B), B, 0, stream>>>(cursor, NN);
  k_degi<<<2048, B, 0, stream>>>(dst, degi, NE);
  k_dinv<<<cdiv(NN, B), B, 0, stream>>>(degi, dinv, NN);
  k_scan<<<1, 1024, 0, stream>>>(degi, rowstart);
  k_fillcsr<<<4096, B, 0, stream>>>(src, dst, rowstart, cursor, dinv, csr_src, csr_nrm, NE);

  // ---- layer 1: x(13) -> 64, relu ----
  k_mm<13, 64, 4><<<cdiv(NN, 4), B, 0, stream>>>(x, W1, bufT, NN);
  k_gather64<true><<<cdiv(NN * 64, B), B, 0, stream>>>(bufT, rowstart, csr_src, csr_nrm, dinv, b1, bufH);

  // ---- layer 2: 64 -> 64, relu ----
  k_mm<64, 64, 4><<<cdiv(NN, 4), B, 0, stream>>>(bufH, W2, bufT, NN);
  k_gather64<true><<<cdiv(NN * 64, B), B, 0, stream>>>(bufT, rowstart, csr_src, csr_nrm, dinv, b2, bufH);

  // ---- layer 3: 64 -> 32, fused with pool partial sums ----
  k_mm<64, 32, 8><<<cdiv(NN, 8), B, 0, stream>>>(bufH, W3, bufT, NN);
  k_zero_f<<<cdiv(NG * 32, B), B, 0, stream>>>(psum, NG * 32);
  k_gather32_pool<<<cdiv(NN * 64, B), B, 0, stream>>>(bufT, rowstart, csr_src, csr_nrm, dinv, b3, batch, psum);

  // ---- finalize mean ----
  k_finalize<<<cdiv(NG * 32, B), B, 0, stream>>>(psum, batch, out);
}